// Round 15
// baseline (510.884 us; speedup 1.0000x reference)
//
#include <hip/hip_runtime.h>
#include <hip/hip_bf16.h>
#include <math.h>

// ---------------------------------------------------------------------------
// GaussianState: out(b) = Re logsumexp( lo(b,0), log(prod s)+lo(b,1) )
//   lo(b,h) = log Pf(W) + 63*ln2 - i*pi + lt(h);  lt = -sum(v^2)/8
// W: 128x128 complex skew, interleaved order. Rank-4 elimination with static
// 4x4 block pivots: D^-1 = -(1/PfD)*adj; z_q[row] from own-row U's; update
// W[r][c] += sum_q z_q[r]*U_q[c].  31 barriers + tail.  Pf = prod PfD * tail.
// Round 15: __launch_bounds__(512,1) -- grid is 1 block/CU, so the (512,2)
// 128-VGPR cap was pure loss; rank-4 needs ~170 VGPR. Fixes round 14's
// 1.4 GB/dispatch scratch-spill regression. Math unchanged.
// ---------------------------------------------------------------------------

#define PI_D  3.14159265358979323846264338328
#define LN2_D 0.69314718055994530941723212146

typedef float f32x2 __attribute__((ext_vector_type(2)));

__device__ __forceinline__ f32x2 cfma(f32x2 a, f32x2 z, f32x2 u) {  // a + z*u
    a = __builtin_elementwise_fma((f32x2){z.x, z.x}, u, a);
    a = __builtin_elementwise_fma((f32x2){-z.y, z.y}, (f32x2){u.y, u.x}, a);
    return a;
}
__device__ __forceinline__ f32x2 cfms(f32x2 a, f32x2 z, f32x2 u) {  // a - z*u
    a = __builtin_elementwise_fma((f32x2){-z.x, -z.x}, u, a);
    a = __builtin_elementwise_fma((f32x2){z.y, -z.y}, (f32x2){u.y, u.x}, a);
    return a;
}
__device__ __forceinline__ f32x2 cmul(f32x2 z, f32x2 u) {
    return cfma((f32x2){0.0f, 0.0f}, z, u);
}

__device__ __forceinline__ int sniff_mode(const void* x) {
    const unsigned int* u = (const unsigned int*)x;
    unsigned int lo = u[0], hi = u[1];
    if ((hi == 0x3FF00000u || hi == 0xBFF00000u) && lo == 0u) return 1;       // f64
    unsigned short a = (unsigned short)(lo & 0xFFFFu);
    unsigned short b = (unsigned short)(lo >> 16);
    if ((a == 0x3F80u || a == 0xBF80u) && (b == 0x3F80u || b == 0xBF80u)) return 2; // bf16
    return 0;                                                                  // f32
}

__device__ __forceinline__ double ld_in(const void* p, int idx, int mode) {
    if (mode == 1) return ((const double*)p)[idx];
    if (mode == 2) {
        unsigned int w = ((unsigned int)((const unsigned short*)p)[idx]) << 16;
        return (double)__uint_as_float(w);
    }
    return (double)((const float*)p)[idx];
}

// G(p,q) = -H[p][q]/2 from upper-tri storage of H (f32)
__device__ __forceinline__ float Gq(const float* Hu, int p, int q) {
    if (p == q) return 0.0f;
    int i = (p < q) ? p : q;
    int j = (p < q) ? q : p;
    float g = -0.5f * Hu[(i * (255 - i)) / 2 + (j - i - 1)];
    return (p < q) ? g : -g;
}

// W'(rn,cn) in interleaved order: even index -> old top q=n>>1, odd -> bottom.
__device__ __forceinline__ void Wq(const float* Hu, const float* tsg,
                                   int rn, int cn, float& re, float& im) {
    int A = rn >> 1, B = cn >> 1;
    if ((cn & 1) == 0) {
        if ((rn & 1) == 0) {
            re = 0.5f * (-Gq(Hu, 2*A, 2*B)   + Gq(Hu, 2*A+1, 2*B+1));
            im = 0.5f * (-Gq(Hu, 2*A, 2*B+1) - Gq(Hu, 2*A+1, 2*B));
        } else {
            int pA = (A + 1) & 63; float tA = tsg[A];
            float Fre = 0.5f * ( tA * Gq(Hu, 2*B, 2*A+1) + Gq(Hu, 2*B+1, 2*pA) );
            float Fim = 0.5f * ( -Gq(Hu, 2*B, 2*pA) + tA * Gq(Hu, 2*B+1, 2*A+1) );
            float Mim = 0.5f * ((B == A ? tA : 0.0f) - (B == pA ? 1.0f : 0.0f));
            re = Fre; im = Mim + Fim;
        }
    } else {
        if ((rn & 1) == 0) {
            int pB = (B + 1) & 63; float tB = tsg[B];
            float Fre = 0.5f * ( tB * Gq(Hu, 2*A, 2*B+1) + Gq(Hu, 2*A+1, 2*pB) );
            float Fim = 0.5f * ( -Gq(Hu, 2*A, 2*pB) + tB * Gq(Hu, 2*A+1, 2*B+1) );
            float Mim = 0.5f * ((A == B ? tB : 0.0f) - (A == pB ? 1.0f : 0.0f));
            re = -Fre; im = -Mim - Fim;
        } else {
            int pA = (A + 1) & 63, pB = (B + 1) & 63;
            float tA = tsg[A], tB = tsg[B];
            re = 0.5f * ( -tA * tB * Gq(Hu, 2*A+1, 2*B+1) + Gq(Hu, 2*pA, 2*pB) );
            im = 0.5f * (  tA * Gq(Hu, 2*A+1, 2*pB) + tB * Gq(Hu, 2*pA, 2*B+1) );
        }
    }
}

// --- per-(sample,ham) Pfaffian via 4x4-block-pivot elimination -------------
// grid 256 = (b,h); 512 threads: t -> cols [8g,8g+8) g=t&15,
// rows {rb,rb+32,rb+64,rb+96} rb=t>>4.
extern "C" __global__ void __launch_bounds__(512, 1)
GaussianState_24318104830346_kernel(const void* xin, const void* h1,
                                    const void* h2, double* lows) {
    const int t   = threadIdx.x;
    const int bid = blockIdx.x;
    const int b = bid & 127, h = bid >> 7;
    const int g    = t & 15;
    const int rb   = t >> 4;
    const int lane = t & 63;
    const int wid  = t >> 6;

    __shared__ float  tsg[64];
    __shared__ float4 ybuf[2][2][136];        // [parity][pair][XI16(row)]
    __shared__ double red[8];
    __shared__ float  Hu[8128];

    const int mode = sniff_mode(xin);
    const void* raw = h ? h2 : h1;

    // stage upper-tri H + accumulate sum(v^2) for lt
    double ss = 0.0;
    for (int f = t; f < 8128; f += 512) {
        double v = ld_in(raw, f, mode);
        Hu[f] = (float)v;
        ss += v * v;
    }
#pragma unroll
    for (int off = 32; off >= 1; off >>= 1) ss += __shfl_xor(ss, off, 64);
    if (lane == 0) red[wid] = ss;

    if (t < 64) {
        float sA = (float)ld_in(xin, b * 64 + t, mode);
        float sB = (float)ld_in(xin, b * 64 + ((t + 1) & 63), mode);
        float tt = sA * sB;
        if (t == 63) tt = -tt;
        tsg[t] = tt;
    }
    __syncthreads();

    // build W' fragment: 4 strata x 8 cols, packed (re,im) in f32x2
    f32x2 acc[4][8];
#pragma unroll
    for (int s = 0; s < 4; ++s)
#pragma unroll
        for (int j = 0; j < 8; ++j) {
            float re, im;
            Wq(Hu, tsg, rb + 32 * s, 8 * g + j, re, im);
            acc[s][j] = (f32x2){re, im};
        }

    const int cb = 8 * g + (g >> 1);          // XI16 base of col range
    const int ob = rb + (rb >> 4);            // XI16 base of own rows (+34*s)

    f32x2 sg = (f32x2){1.0f, 0.0f};           // prod 4*PfD (uniform)

    for (int K = 0; K < 16; ++K) {
#pragma unroll
        for (int m = 0; m < 2; ++m) {
            const int k4 = 2 * K + m;         // pivot block: cols 4k4..4k4+3
            if (k4 < 31) {
                // stage both col pairs (stager group g == K; j0 static)
                if (g == K) {
                    const int j0 = 4 * m;
#pragma unroll
                    for (int s = 0; s < 4; ++s) {
                        if (rb + 32 * s >= 4 * k4) {
                            ybuf[m][0][ob + 34 * s] =
                                make_float4(acc[s][j0].x,     acc[s][j0].y,
                                            acc[s][j0 + 1].x, acc[s][j0 + 1].y);
                            ybuf[m][1][ob + 34 * s] =
                                make_float4(acc[s][j0 + 2].x, acc[s][j0 + 2].y,
                                            acc[s][j0 + 3].x, acc[s][j0 + 3].y);
                        }
                    }
                }
                __syncthreads();

                // D block + PfD + Dinv products (all threads, uniform)
                const int rp = 4 * k4;
                const int x0 = rp + (rp >> 4);            // XI16(4k4)
                float4 q00 = ybuf[m][0][x0];              // row0: (., d01)
                float4 q10 = ybuf[m][1][x0];              // row0: (d02, d03)
                float4 q11 = ybuf[m][1][x0 + 1];          // row1: (d12, d13)
                float4 q12 = ybuf[m][1][x0 + 2];          // row2: (.,  d23)
                f32x2 d01 = (f32x2){q00.z, q00.w};
                f32x2 d02 = (f32x2){q10.x, q10.y};
                f32x2 d03 = (f32x2){q10.z, q10.w};
                f32x2 d12 = (f32x2){q11.x, q11.y};
                f32x2 d13 = (f32x2){q11.z, q11.w};
                f32x2 d23 = (f32x2){q12.z, q12.w};
                f32x2 pf = cmul(d01, d23);
                pf = cfms(pf, d02, d13);
                pf = cfma(pf, d03, d12);                  // PfD
                float m2  = pf.x * pf.x + pf.y * pf.y;
                float den = __builtin_amdgcn_rcpf(m2);
                f32x2 w = (f32x2){-pf.x * den, pf.y * den};   // -1/PfD
                f32x2 P1 = cmul(w, d23), P2 = cmul(w, d13), P3 = cmul(w, d12);
                f32x2 P4 = cmul(w, d03), P5 = cmul(w, d02), P6 = cmul(w, d01);
                // sign: sg *= 4*PfD
                f32x2 t4 = cmul(sg, pf);
                sg = (f32x2){4.0f * t4.x, 4.0f * t4.y};

                if (wid + 24 > k4) {                      // any stratum live
                    // per-stratum row factors z[s][0..3]
                    f32x2 z[4][4];
#pragma unroll
                    for (int s = 0; s < 4; ++s) {
                        if (wid + 8 * s > k4) {           // wave-uniform
                            float4 o0 = ybuf[m][0][ob + 34 * s];
                            float4 o1 = ybuf[m][1][ob + 34 * s];
                            f32x2 U0 = (f32x2){o0.x, o0.y};
                            f32x2 U1 = (f32x2){o0.z, o0.w};
                            f32x2 U2 = (f32x2){o1.x, o1.y};
                            f32x2 U3 = (f32x2){o1.z, o1.w};
                            f32x2 z0 = cmul(P2, U2);
                            z0 = cfms(z0, P1, U1);
                            z0 = cfms(z0, P3, U3);
                            f32x2 z1 = cmul(P1, U0);
                            z1 = cfms(z1, P4, U2);
                            z1 = cfma(z1, P5, U3);
                            f32x2 z2 = cmul(P4, U1);
                            z2 = cfms(z2, P2, U0);
                            z2 = cfms(z2, P6, U3);
                            f32x2 z3 = cmul(P3, U0);
                            z3 = cfms(z3, P5, U1);
                            z3 = cfma(z3, P6, U2);
                            z[s][0] = z0; z[s][1] = z1;
                            z[s][2] = z2; z[s][3] = z3;
                        }
                    }
                    // j-outer update: read cols transiently, update 4 strata
#pragma unroll
                    for (int j = 0; j < 8; ++j) {
                        float4 a0 = ybuf[m][0][cb + j];
                        float4 a1 = ybuf[m][1][cb + j];
                        f32x2 u0 = (f32x2){a0.x, a0.y};
                        f32x2 u1 = (f32x2){a0.z, a0.w};
                        f32x2 u2 = (f32x2){a1.x, a1.y};
                        f32x2 u3 = (f32x2){a1.z, a1.w};
#pragma unroll
                        for (int s = 0; s < 4; ++s) {
                            if (wid + 8 * s > k4) {       // wave-uniform
                                f32x2 a = acc[s][j];
                                a = cfma(a, z[s][0], u0);
                                a = cfma(a, z[s][1], u1);
                                a = cfma(a, z[s][2], u2);
                                a = cfma(a, z[s][3], u3);
                                acc[s][j] = a;
                            }
                        }
                    }
                }
            }
        }
    }

    // tail: Pf of the remaining 4x4 block (rows/cols 124..127)
    __syncthreads();
    if (g == 15 && rb >= 28) {                // threads own rows 124..127 (s=3)
        ybuf[1][0][rb - 28] = make_float4(acc[3][4].x, acc[3][4].y,
                                          acc[3][5].x, acc[3][5].y);
        ybuf[1][1][rb - 28] = make_float4(acc[3][6].x, acc[3][6].y,
                                          acc[3][7].x, acc[3][7].y);
    }
    __syncthreads();
    if (t == 0) {
        float4 q00 = ybuf[1][0][0];
        float4 q10 = ybuf[1][1][0];
        float4 q11 = ybuf[1][1][1];
        float4 q12 = ybuf[1][1][2];
        f32x2 d01 = (f32x2){q00.z, q00.w};
        f32x2 d02 = (f32x2){q10.x, q10.y};
        f32x2 d03 = (f32x2){q10.z, q10.w};
        f32x2 d12 = (f32x2){q11.x, q11.y};
        f32x2 d13 = (f32x2){q11.z, q11.w};
        f32x2 d23 = (f32x2){q12.z, q12.w};
        f32x2 pf = cmul(d01, d23);
        pf = cfms(pf, d02, d13);
        pf = cfma(pf, d03, d12);                          // Pf_final
        f32x2 tot = cmul(sg, pf);
        tot = (f32x2){4.0f * tot.x, 4.0f * tot.y};        // = 2^64 * Pf(W)
        float mag = sqrtf(tot.x * tot.x + tot.y * tot.y);
        double lt = -(red[0] + red[1] + red[2] + red[3] +
                      red[4] + red[5] + red[6] + red[7]) / 8.0;   // tr(H^2)/16
        double* lo = lows + (h * 128 + b) * 2;
        lo[0] = (double)logf(mag) - LN2_D + lt;   // log|Pf| + 63 ln2 + lt
        lo[1] = atan2((double)tot.y, (double)tot.x) - PI_D;
    }
}

// --- combine: out(b) = Re logsumexp(lo1, log(s_prod)+lo2) as f32 -----------
extern "C" __global__ void gs_combine(const void* xin, const double* lows,
                                      float* out, int out_size) {
    int t = threadIdx.x;
    int mode = sniff_mode(xin);
    if (t < 128) {
        const double* lo1 = lows + t * 2;
        const double* lo2 = lows + (128 + t) * 2;
        double p = 1.0;
        for (int k = 0; k < 64; ++k) p *= ld_in(xin, t * 64 + k, mode);
        double a1r = lo1[0], a1i = lo1[1];
        double a2r = lo2[0], a2i = lo2[1] + (p < 0.0 ? PI_D : 0.0);
        double m = fmax(a1r, a2r);
        double s1, c1, s2, c2;
        sincos(a1i, &s1, &c1);
        sincos(a2i, &s2, &c2);
        double e1 = exp(a1r - m), e2 = exp(a2r - m);
        double zr = e1 * c1 + e2 * c2;
        double zi = e1 * s1 + e2 * s2;
        double outre = m + 0.5 * log(zr * zr + zi * zi);
        double outim = atan2(zi, zr);
        if (out_size >= 256) {                 // fallback: complex interleaved
            out[2 * t]     = (float)outre;
            out[2 * t + 1] = (float)outim;
        } else if (t < out_size) {             // primary: real part only (128)
            out[t] = (float)outre;
        }
    }
    for (int q = 256 + t; q < out_size; q += blockDim.x) out[q] = 0.0f;
}

extern "C" void kernel_launch(void* const* d_in, const int* in_sizes, int n_in,
                              void* d_out, int out_size, void* d_ws, size_t ws_size,
                              hipStream_t stream) {
    (void)ws_size;
    int xi = 0;
    for (int i = 0; i < n_in; ++i) if (in_sizes[i] == 8192) { xi = i; break; }
    const void* x = d_in[xi];
    const void* hh[2] = {nullptr, nullptr};
    int np = 0;
    for (int i = 0; i < n_in && np < 2; ++i) if (i != xi) hh[np++] = d_in[i];

    double* lows = (double*)d_ws;   // 512 doubles, fully rewritten every call

    GaussianState_24318104830346_kernel<<<256, 512, 0, stream>>>(x, hh[0], hh[1], lows);
    gs_combine<<<1, 256, 0, stream>>>(x, lows, (float*)d_out, out_size);
}

// Round 16
// 510.003 us; speedup vs baseline: 1.0017x; 1.0017x over previous
//
#include <hip/hip_runtime.h>
#include <hip/hip_bf16.h>
#include <math.h>

// ---------------------------------------------------------------------------
// GaussianState: out(b) = Re logsumexp( lo(b,0), log(prod s)+lo(b,1) )
//   lo(b,h) = log Pf(W) + 63*ln2 - i*pi + lt(h);  lt = -sum(v^2)/8
// W: 128x128 complex skew, interleaved order. Rank-4 elimination with static
// 4x4 block pivots: D^-1 = -(1/PfD)*adj; z_q[row] from own-row U's; update
// W[r][c] += sum_q z_q[r]*U_q[c].  31 barriers + tail.  Pf = prod PfD * tail.
// Round 16: amdgpu_waves_per_eu(2,2) — pin the allocator's occupancy target
// to 2 waves/EU (our exact residency: 8 waves / 4 SIMDs, 1 block/CU) so the
// VGPR budget is 256 not 128. launch_bounds min-waves only sets a minimum;
// the allocator chose 4 waves/EU and spilled 1.4 GB/dispatch (rounds 14-15).
// ---------------------------------------------------------------------------

#define PI_D  3.14159265358979323846264338328
#define LN2_D 0.69314718055994530941723212146

typedef float f32x2 __attribute__((ext_vector_type(2)));

__device__ __forceinline__ f32x2 cfma(f32x2 a, f32x2 z, f32x2 u) {  // a + z*u
    a = __builtin_elementwise_fma((f32x2){z.x, z.x}, u, a);
    a = __builtin_elementwise_fma((f32x2){-z.y, z.y}, (f32x2){u.y, u.x}, a);
    return a;
}
__device__ __forceinline__ f32x2 cfms(f32x2 a, f32x2 z, f32x2 u) {  // a - z*u
    a = __builtin_elementwise_fma((f32x2){-z.x, -z.x}, u, a);
    a = __builtin_elementwise_fma((f32x2){z.y, -z.y}, (f32x2){u.y, u.x}, a);
    return a;
}
__device__ __forceinline__ f32x2 cmul(f32x2 z, f32x2 u) {
    return cfma((f32x2){0.0f, 0.0f}, z, u);
}

__device__ __forceinline__ int sniff_mode(const void* x) {
    const unsigned int* u = (const unsigned int*)x;
    unsigned int lo = u[0], hi = u[1];
    if ((hi == 0x3FF00000u || hi == 0xBFF00000u) && lo == 0u) return 1;       // f64
    unsigned short a = (unsigned short)(lo & 0xFFFFu);
    unsigned short b = (unsigned short)(lo >> 16);
    if ((a == 0x3F80u || a == 0xBF80u) && (b == 0x3F80u || b == 0xBF80u)) return 2; // bf16
    return 0;                                                                  // f32
}

__device__ __forceinline__ double ld_in(const void* p, int idx, int mode) {
    if (mode == 1) return ((const double*)p)[idx];
    if (mode == 2) {
        unsigned int w = ((unsigned int)((const unsigned short*)p)[idx]) << 16;
        return (double)__uint_as_float(w);
    }
    return (double)((const float*)p)[idx];
}

// G(p,q) = -H[p][q]/2 from upper-tri storage of H (f32)
__device__ __forceinline__ float Gq(const float* Hu, int p, int q) {
    if (p == q) return 0.0f;
    int i = (p < q) ? p : q;
    int j = (p < q) ? q : p;
    float g = -0.5f * Hu[(i * (255 - i)) / 2 + (j - i - 1)];
    return (p < q) ? g : -g;
}

// W'(rn,cn) in interleaved order: even index -> old top q=n>>1, odd -> bottom.
__device__ __forceinline__ void Wq(const float* Hu, const float* tsg,
                                   int rn, int cn, float& re, float& im) {
    int A = rn >> 1, B = cn >> 1;
    if ((cn & 1) == 0) {
        if ((rn & 1) == 0) {
            re = 0.5f * (-Gq(Hu, 2*A, 2*B)   + Gq(Hu, 2*A+1, 2*B+1));
            im = 0.5f * (-Gq(Hu, 2*A, 2*B+1) - Gq(Hu, 2*A+1, 2*B));
        } else {
            int pA = (A + 1) & 63; float tA = tsg[A];
            float Fre = 0.5f * ( tA * Gq(Hu, 2*B, 2*A+1) + Gq(Hu, 2*B+1, 2*pA) );
            float Fim = 0.5f * ( -Gq(Hu, 2*B, 2*pA) + tA * Gq(Hu, 2*B+1, 2*A+1) );
            float Mim = 0.5f * ((B == A ? tA : 0.0f) - (B == pA ? 1.0f : 0.0f));
            re = Fre; im = Mim + Fim;
        }
    } else {
        if ((rn & 1) == 0) {
            int pB = (B + 1) & 63; float tB = tsg[B];
            float Fre = 0.5f * ( tB * Gq(Hu, 2*A, 2*B+1) + Gq(Hu, 2*A+1, 2*pB) );
            float Fim = 0.5f * ( -Gq(Hu, 2*A, 2*pB) + tB * Gq(Hu, 2*A+1, 2*B+1) );
            float Mim = 0.5f * ((A == B ? tB : 0.0f) - (A == pB ? 1.0f : 0.0f));
            re = -Fre; im = -Mim - Fim;
        } else {
            int pA = (A + 1) & 63, pB = (B + 1) & 63;
            float tA = tsg[A], tB = tsg[B];
            re = 0.5f * ( -tA * tB * Gq(Hu, 2*A+1, 2*B+1) + Gq(Hu, 2*pA, 2*pB) );
            im = 0.5f * (  tA * Gq(Hu, 2*A+1, 2*pB) + tB * Gq(Hu, 2*pA, 2*B+1) );
        }
    }
}

// --- per-(sample,ham) Pfaffian via 4x4-block-pivot elimination -------------
// grid 256 = (b,h); 512 threads: t -> cols [8g,8g+8) g=t&15,
// rows {rb,rb+32,rb+64,rb+96} rb=t>>4.
extern "C" __global__ void __launch_bounds__(512)
__attribute__((amdgpu_waves_per_eu(2, 2)))
GaussianState_24318104830346_kernel(const void* xin, const void* h1,
                                    const void* h2, double* lows) {
    const int t   = threadIdx.x;
    const int bid = blockIdx.x;
    const int b = bid & 127, h = bid >> 7;
    const int g    = t & 15;
    const int rb   = t >> 4;
    const int lane = t & 63;
    const int wid  = t >> 6;

    __shared__ float  tsg[64];
    __shared__ float4 ybuf[2][2][136];        // [parity][pair][XI16(row)]
    __shared__ double red[8];
    __shared__ float  Hu[8128];

    const int mode = sniff_mode(xin);
    const void* raw = h ? h2 : h1;

    // stage upper-tri H + accumulate sum(v^2) for lt
    double ss = 0.0;
    for (int f = t; f < 8128; f += 512) {
        double v = ld_in(raw, f, mode);
        Hu[f] = (float)v;
        ss += v * v;
    }
#pragma unroll
    for (int off = 32; off >= 1; off >>= 1) ss += __shfl_xor(ss, off, 64);
    if (lane == 0) red[wid] = ss;

    if (t < 64) {
        float sA = (float)ld_in(xin, b * 64 + t, mode);
        float sB = (float)ld_in(xin, b * 64 + ((t + 1) & 63), mode);
        float tt = sA * sB;
        if (t == 63) tt = -tt;
        tsg[t] = tt;
    }
    __syncthreads();

    // build W' fragment: 4 strata x 8 cols, packed (re,im) in f32x2
    f32x2 acc[4][8];
#pragma unroll
    for (int s = 0; s < 4; ++s)
#pragma unroll
        for (int j = 0; j < 8; ++j) {
            float re, im;
            Wq(Hu, tsg, rb + 32 * s, 8 * g + j, re, im);
            acc[s][j] = (f32x2){re, im};
        }

    const int cb = 8 * g + (g >> 1);          // XI16 base of col range
    const int ob = rb + (rb >> 4);            // XI16 base of own rows (+34*s)

    f32x2 sg = (f32x2){1.0f, 0.0f};           // prod 4*PfD (uniform)

    for (int K = 0; K < 16; ++K) {
#pragma unroll
        for (int m = 0; m < 2; ++m) {
            const int k4 = 2 * K + m;         // pivot block: cols 4k4..4k4+3
            if (k4 < 31) {
                // stage both col pairs (stager group g == K; j0 static)
                if (g == K) {
                    const int j0 = 4 * m;
#pragma unroll
                    for (int s = 0; s < 4; ++s) {
                        if (rb + 32 * s >= 4 * k4) {
                            ybuf[m][0][ob + 34 * s] =
                                make_float4(acc[s][j0].x,     acc[s][j0].y,
                                            acc[s][j0 + 1].x, acc[s][j0 + 1].y);
                            ybuf[m][1][ob + 34 * s] =
                                make_float4(acc[s][j0 + 2].x, acc[s][j0 + 2].y,
                                            acc[s][j0 + 3].x, acc[s][j0 + 3].y);
                        }
                    }
                }
                __syncthreads();

                // D block + PfD + Dinv products (all threads, uniform)
                const int rp = 4 * k4;
                const int x0 = rp + (rp >> 4);            // XI16(4k4)
                float4 q00 = ybuf[m][0][x0];              // row0: (., d01)
                float4 q10 = ybuf[m][1][x0];              // row0: (d02, d03)
                float4 q11 = ybuf[m][1][x0 + 1];          // row1: (d12, d13)
                float4 q12 = ybuf[m][1][x0 + 2];          // row2: (.,  d23)
                f32x2 d01 = (f32x2){q00.z, q00.w};
                f32x2 d02 = (f32x2){q10.x, q10.y};
                f32x2 d03 = (f32x2){q10.z, q10.w};
                f32x2 d12 = (f32x2){q11.x, q11.y};
                f32x2 d13 = (f32x2){q11.z, q11.w};
                f32x2 d23 = (f32x2){q12.z, q12.w};
                f32x2 pf = cmul(d01, d23);
                pf = cfms(pf, d02, d13);
                pf = cfma(pf, d03, d12);                  // PfD
                float m2  = pf.x * pf.x + pf.y * pf.y;
                float den = __builtin_amdgcn_rcpf(m2);
                f32x2 w = (f32x2){-pf.x * den, pf.y * den};   // -1/PfD
                f32x2 P1 = cmul(w, d23), P2 = cmul(w, d13), P3 = cmul(w, d12);
                f32x2 P4 = cmul(w, d03), P5 = cmul(w, d02), P6 = cmul(w, d01);
                // sign: sg *= 4*PfD
                f32x2 t4 = cmul(sg, pf);
                sg = (f32x2){4.0f * t4.x, 4.0f * t4.y};

                if (wid + 24 > k4) {                      // any stratum live
                    // per-stratum row factors z[s][0..3]
                    f32x2 z[4][4];
#pragma unroll
                    for (int s = 0; s < 4; ++s) {
                        if (wid + 8 * s > k4) {           // wave-uniform
                            float4 o0 = ybuf[m][0][ob + 34 * s];
                            float4 o1 = ybuf[m][1][ob + 34 * s];
                            f32x2 U0 = (f32x2){o0.x, o0.y};
                            f32x2 U1 = (f32x2){o0.z, o0.w};
                            f32x2 U2 = (f32x2){o1.x, o1.y};
                            f32x2 U3 = (f32x2){o1.z, o1.w};
                            f32x2 z0 = cmul(P2, U2);
                            z0 = cfms(z0, P1, U1);
                            z0 = cfms(z0, P3, U3);
                            f32x2 z1 = cmul(P1, U0);
                            z1 = cfms(z1, P4, U2);
                            z1 = cfma(z1, P5, U3);
                            f32x2 z2 = cmul(P4, U1);
                            z2 = cfms(z2, P2, U0);
                            z2 = cfms(z2, P6, U3);
                            f32x2 z3 = cmul(P3, U0);
                            z3 = cfms(z3, P5, U1);
                            z3 = cfma(z3, P6, U2);
                            z[s][0] = z0; z[s][1] = z1;
                            z[s][2] = z2; z[s][3] = z3;
                        }
                    }
                    // j-outer update: read cols transiently, update 4 strata
#pragma unroll
                    for (int j = 0; j < 8; ++j) {
                        float4 a0 = ybuf[m][0][cb + j];
                        float4 a1 = ybuf[m][1][cb + j];
                        f32x2 u0 = (f32x2){a0.x, a0.y};
                        f32x2 u1 = (f32x2){a0.z, a0.w};
                        f32x2 u2 = (f32x2){a1.x, a1.y};
                        f32x2 u3 = (f32x2){a1.z, a1.w};
#pragma unroll
                        for (int s = 0; s < 4; ++s) {
                            if (wid + 8 * s > k4) {       // wave-uniform
                                f32x2 a = acc[s][j];
                                a = cfma(a, z[s][0], u0);
                                a = cfma(a, z[s][1], u1);
                                a = cfma(a, z[s][2], u2);
                                a = cfma(a, z[s][3], u3);
                                acc[s][j] = a;
                            }
                        }
                    }
                }
            }
        }
    }

    // tail: Pf of the remaining 4x4 block (rows/cols 124..127)
    __syncthreads();
    if (g == 15 && rb >= 28) {                // threads own rows 124..127 (s=3)
        ybuf[1][0][rb - 28] = make_float4(acc[3][4].x, acc[3][4].y,
                                          acc[3][5].x, acc[3][5].y);
        ybuf[1][1][rb - 28] = make_float4(acc[3][6].x, acc[3][6].y,
                                          acc[3][7].x, acc[3][7].y);
    }
    __syncthreads();
    if (t == 0) {
        float4 q00 = ybuf[1][0][0];
        float4 q10 = ybuf[1][1][0];
        float4 q11 = ybuf[1][1][1];
        float4 q12 = ybuf[1][1][2];
        f32x2 d01 = (f32x2){q00.z, q00.w};
        f32x2 d02 = (f32x2){q10.x, q10.y};
        f32x2 d03 = (f32x2){q10.z, q10.w};
        f32x2 d12 = (f32x2){q11.x, q11.y};
        f32x2 d13 = (f32x2){q11.z, q11.w};
        f32x2 d23 = (f32x2){q12.z, q12.w};
        f32x2 pf = cmul(d01, d23);
        pf = cfms(pf, d02, d13);
        pf = cfma(pf, d03, d12);                          // Pf_final
        f32x2 tot = cmul(sg, pf);
        tot = (f32x2){4.0f * tot.x, 4.0f * tot.y};        // = 2^64 * Pf(W)
        float mag = sqrtf(tot.x * tot.x + tot.y * tot.y);
        double lt = -(red[0] + red[1] + red[2] + red[3] +
                      red[4] + red[5] + red[6] + red[7]) / 8.0;   // tr(H^2)/16
        double* lo = lows + (h * 128 + b) * 2;
        lo[0] = (double)logf(mag) - LN2_D + lt;   // log|Pf| + 63 ln2 + lt
        lo[1] = atan2((double)tot.y, (double)tot.x) - PI_D;
    }
}

// --- combine: out(b) = Re logsumexp(lo1, log(s_prod)+lo2) as f32 -----------
extern "C" __global__ void gs_combine(const void* xin, const double* lows,
                                      float* out, int out_size) {
    int t = threadIdx.x;
    int mode = sniff_mode(xin);
    if (t < 128) {
        const double* lo1 = lows + t * 2;
        const double* lo2 = lows + (128 + t) * 2;
        double p = 1.0;
        for (int k = 0; k < 64; ++k) p *= ld_in(xin, t * 64 + k, mode);
        double a1r = lo1[0], a1i = lo1[1];
        double a2r = lo2[0], a2i = lo2[1] + (p < 0.0 ? PI_D : 0.0);
        double m = fmax(a1r, a2r);
        double s1, c1, s2, c2;
        sincos(a1i, &s1, &c1);
        sincos(a2i, &s2, &c2);
        double e1 = exp(a1r - m), e2 = exp(a2r - m);
        double zr = e1 * c1 + e2 * c2;
        double zi = e1 * s1 + e2 * s2;
        double outre = m + 0.5 * log(zr * zr + zi * zi);
        double outim = atan2(zi, zr);
        if (out_size >= 256) {                 // fallback: complex interleaved
            out[2 * t]     = (float)outre;
            out[2 * t + 1] = (float)outim;
        } else if (t < out_size) {             // primary: real part only (128)
            out[t] = (float)outre;
        }
    }
    for (int q = 256 + t; q < out_size; q += blockDim.x) out[q] = 0.0f;
}

extern "C" void kernel_launch(void* const* d_in, const int* in_sizes, int n_in,
                              void* d_out, int out_size, void* d_ws, size_t ws_size,
                              hipStream_t stream) {
    (void)ws_size;
    int xi = 0;
    for (int i = 0; i < n_in; ++i) if (in_sizes[i] == 8192) { xi = i; break; }
    const void* x = d_in[xi];
    const void* hh[2] = {nullptr, nullptr};
    int np = 0;
    for (int i = 0; i < n_in && np < 2; ++i) if (i != xi) hh[np++] = d_in[i];

    double* lows = (double*)d_ws;   // 512 doubles, fully rewritten every call

    GaussianState_24318104830346_kernel<<<256, 512, 0, stream>>>(x, hh[0], hh[1], lows);
    gs_combine<<<1, 256, 0, stream>>>(x, lows, (float*)d_out, out_size);
}

// Round 17
// 82.784 us; speedup vs baseline: 6.1713x; 6.1606x over previous
//
#include <hip/hip_runtime.h>
#include <hip/hip_bf16.h>
#include <math.h>

// ---------------------------------------------------------------------------
// GaussianState: out(b) = Re logsumexp( lo(b,0), log(prod s)+lo(b,1) )
//   lo(b,h) = log Pf(W) + 63*ln2 - i*pi + lt(h);  lt = -sum(v^2)/8
// W: 128x128 complex skew, interleaved order; rank-2 Parlett-Reid with static
// 2x2 pivots (round-12 arithmetic, absmax-0-validated). Round 17: remapped
// ownership -- thread t: col group gg=t>>5 (cols [8gg,8gg+8)), rows q+32s,
// q=t&31. Wave w owns cols [16w,16w+16) -> COLUMN retirement is wave-uniform
// (k < 8w+7) on top of row-strata retirement (k <= 16s+14): ~1.5x less
// update work; col reads become 32-lane broadcasts. 72-96 VGPR (no spill).
// ---------------------------------------------------------------------------

#define PI_D  3.14159265358979323846264338328
#define LN2_D 0.69314718055994530941723212146

typedef float f32x2 __attribute__((ext_vector_type(2)));

__device__ __forceinline__ int sniff_mode(const void* x) {
    const unsigned int* u = (const unsigned int*)x;
    unsigned int lo = u[0], hi = u[1];
    if ((hi == 0x3FF00000u || hi == 0xBFF00000u) && lo == 0u) return 1;       // f64
    unsigned short a = (unsigned short)(lo & 0xFFFFu);
    unsigned short b = (unsigned short)(lo >> 16);
    if ((a == 0x3F80u || a == 0xBF80u) && (b == 0x3F80u || b == 0xBF80u)) return 2; // bf16
    return 0;                                                                  // f32
}

__device__ __forceinline__ double ld_in(const void* p, int idx, int mode) {
    if (mode == 1) return ((const double*)p)[idx];
    if (mode == 2) {
        unsigned int w = ((unsigned int)((const unsigned short*)p)[idx]) << 16;
        return (double)__uint_as_float(w);
    }
    return (double)((const float*)p)[idx];
}

// G(p,q) = -H[p][q]/2 from upper-tri storage of H (f32)
__device__ __forceinline__ float Gq(const float* Hu, int p, int q) {
    if (p == q) return 0.0f;
    int i = (p < q) ? p : q;
    int j = (p < q) ? q : p;
    float g = -0.5f * Hu[(i * (255 - i)) / 2 + (j - i - 1)];
    return (p < q) ? g : -g;
}

// W'(rn,cn) in interleaved order: even index -> old top q=n>>1, odd -> bottom.
__device__ __forceinline__ void Wq(const float* Hu, const float* tsg,
                                   int rn, int cn, float& re, float& im) {
    int A = rn >> 1, B = cn >> 1;
    if ((cn & 1) == 0) {
        if ((rn & 1) == 0) {
            re = 0.5f * (-Gq(Hu, 2*A, 2*B)   + Gq(Hu, 2*A+1, 2*B+1));
            im = 0.5f * (-Gq(Hu, 2*A, 2*B+1) - Gq(Hu, 2*A+1, 2*B));
        } else {
            int pA = (A + 1) & 63; float tA = tsg[A];
            float Fre = 0.5f * ( tA * Gq(Hu, 2*B, 2*A+1) + Gq(Hu, 2*B+1, 2*pA) );
            float Fim = 0.5f * ( -Gq(Hu, 2*B, 2*pA) + tA * Gq(Hu, 2*B+1, 2*A+1) );
            float Mim = 0.5f * ((B == A ? tA : 0.0f) - (B == pA ? 1.0f : 0.0f));
            re = Fre; im = Mim + Fim;
        }
    } else {
        if ((rn & 1) == 0) {
            int pB = (B + 1) & 63; float tB = tsg[B];
            float Fre = 0.5f * ( tB * Gq(Hu, 2*A, 2*B+1) + Gq(Hu, 2*A+1, 2*pB) );
            float Fim = 0.5f * ( -Gq(Hu, 2*A, 2*pB) + tB * Gq(Hu, 2*A+1, 2*B+1) );
            float Mim = 0.5f * ((A == B ? tB : 0.0f) - (A == pB ? 1.0f : 0.0f));
            re = -Fre; im = -Mim - Fim;
        } else {
            int pA = (A + 1) & 63, pB = (B + 1) & 63;
            float tA = tsg[A], tB = tsg[B];
            re = 0.5f * ( -tA * tB * Gq(Hu, 2*A+1, 2*B+1) + Gq(Hu, 2*pA, 2*pB) );
            im = 0.5f * (  tA * Gq(Hu, 2*A+1, 2*pB) + tB * Gq(Hu, 2*pA, 2*B+1) );
        }
    }
}

// --- per-(sample,ham) Pfaffian via 2x2-pivot block elimination -------------
// grid 256 = (b,h); 512 threads: gg=t>>5 -> cols [8gg,8gg+8),
// q=t&31 -> rows {q,q+32,q+64,q+96}.
extern "C" __global__ void __launch_bounds__(512)
GaussianState_24318104830346_kernel(const void* xin, const void* h1,
                                    const void* h2, double* lows) {
    const int t   = threadIdx.x;
    const int bid = blockIdx.x;
    const int b = bid & 127, h = bid >> 7;
    const int gg   = t >> 5;                  // col group (wave-half-uniform)
    const int q    = t & 31;                  // row base
    const int lane = t & 63;
    const int wid  = t >> 6;
    const int kdead = 8 * wid + 7;            // wave col-retirement bound

    __shared__ float  tsg[64];
    __shared__ float4 xbuf[2][136];           // XI16-padded staged col pairs
    __shared__ double red[8];
    __shared__ float  Hu[8128];

    const int mode = sniff_mode(xin);
    const void* raw = h ? h2 : h1;

    // stage upper-tri H + accumulate sum(v^2) for lt
    double ss = 0.0;
    for (int f = t; f < 8128; f += 512) {
        double v = ld_in(raw, f, mode);
        Hu[f] = (float)v;
        ss += v * v;
    }
#pragma unroll
    for (int off = 32; off >= 1; off >>= 1) ss += __shfl_xor(ss, off, 64);
    if (lane == 0) red[wid] = ss;

    if (t < 64) {
        float sA = (float)ld_in(xin, b * 64 + t, mode);
        float sB = (float)ld_in(xin, b * 64 + ((t + 1) & 63), mode);
        float tt = sA * sB;
        if (t == 63) tt = -tt;
        tsg[t] = tt;
    }
    __syncthreads();

    // build W' fragment: 4 strata x 8 cols, packed (re,im) in f32x2
    f32x2 acc[4][8];
#pragma unroll
    for (int s = 0; s < 4; ++s)
#pragma unroll
        for (int j = 0; j < 8; ++j) {
            float re, im;
            Wq(Hu, tsg, q + 32 * s, 8 * gg + j, re, im);
            acc[s][j] = (f32x2){re, im};
        }

    const int cb  = 8 * gg + (gg >> 1);       // XI16 base of col range (const/8)
    const int obq = q + (q >> 4);             // XI16 base of own rows (+34*s)

    float sgr = 1.0f, sgi = 0.0f;             // s = prod 2*a_k (all threads)

    for (int K = 0; K < 8; ++K) {
#pragma unroll
        for (int m = 0; m < 8; ++m) {
            const int k = (K << 3) + m;
            if (k < 63) {
                const int par = m & 1;
                // stage pivot col pair 2k,2k+1 (owner col-group; all strata)
                if (gg == (k >> 2)) {
                    const int j2 = 2 * (m & 3);          // static
#pragma unroll
                    for (int s = 0; s < 4; ++s)
                        xbuf[par][obq + 34 * s] =
                            make_float4(acc[s][j2].x, acc[s][j2].y,
                                        acc[s][j2 + 1].x, acc[s][j2 + 1].y);
                }
                __syncthreads();
                // pivot + sign (all threads; keeps history valid everywhere)
                float4 pv = xbuf[par][2 * k + (k >> 3)]; // XI16(2k), broadcast
                float arr = pv.z, aii = pv.w;
                float m2  = arr * arr + aii * aii;
                float den = __builtin_amdgcn_rcpf(m2);
                float ivr = arr * den, ivi = -aii * den;
                float nsr = 2.0f * (sgr * arr - sgi * aii);
                sgi = 2.0f * (sgr * aii + sgi * arr);
                sgr = nsr;
                if (k < kdead) {                         // col-live (wave-uniform)
                    // read the 8 column values ONCE (broadcast across 32 lanes)
                    const float4* bp = &xbuf[par][cb];
                    f32x2 c1[8], c2[8];
#pragma unroll
                    for (int j = 0; j < 8; ++j) {
                        float4 cv = bp[j];
                        c1[j] = (f32x2){cv.x, cv.y};
                        c2[j] = (f32x2){cv.z, cv.w};
                    }
#pragma unroll
                    for (int s = 0; s < 4; ++s) {
                        if (k <= 16 * s + 14) {          // row-live (wave-uniform)
                            float4 own = xbuf[par][obq + 34 * s];
                            float br = own.z * ivr - own.w * ivi;
                            float bi = own.z * ivi + own.w * ivr;
                            float gr = own.x * ivr - own.y * ivi;
                            float gi = own.x * ivi + own.y * ivr;
                            f32x2 bv  = (f32x2){ br,  br};
                            f32x2 bnv = (f32x2){-bi,  bi};
                            f32x2 gv  = (f32x2){-gr, -gr};
                            f32x2 gnv = (f32x2){ gi, -gi};
#pragma unroll
                            for (int j = 0; j < 8; ++j) {
                                f32x2 a = acc[s][j];
                                a = __builtin_elementwise_fma(bv,  c1[j],    a);
                                a = __builtin_elementwise_fma(bnv, c1[j].yx, a);
                                a = __builtin_elementwise_fma(gv,  c2[j],    a);
                                a = __builtin_elementwise_fma(gnv, c2[j].yx, a);
                                acc[s][j] = a;
                            }
                        }
                    }
                }
            }
        }
    }

    __syncthreads();
    if (t == 510)                             // row 126 (q=30,s=3), col 127 (gg=15,j=7)
        xbuf[0][0] = make_float4(acc[3][7].x, acc[3][7].y, 0.0f, 0.0f);
    __syncthreads();
    if (t == 0) {
        float lr = xbuf[0][0].x, li = xbuf[0][0].y;      // a_63
        float snr = sgr * lr - sgi * li;       // s * a_63, |.| = 2^63 |Pf|
        float sni = sgr * li + sgi * lr;
        float mag = sqrtf(snr * snr + sni * sni);
        double lt = -(red[0] + red[1] + red[2] + red[3] +
                      red[4] + red[5] + red[6] + red[7]) / 8.0;   // tr(H^2)/16
        double* lo = lows + (h * 128 + b) * 2;
        lo[0] = (double)logf(mag) + lt;        // = log|Pf| + 63 ln2 + lt
        lo[1] = atan2((double)sni, (double)snr) - PI_D;
    }
}

// --- combine: out(b) = Re logsumexp(lo1, log(s_prod)+lo2) as f32 -----------
extern "C" __global__ void gs_combine(const void* xin, const double* lows,
                                      float* out, int out_size) {
    int t = threadIdx.x;
    int mode = sniff_mode(xin);
    if (t < 128) {
        const double* lo1 = lows + t * 2;
        const double* lo2 = lows + (128 + t) * 2;
        double p = 1.0;
        for (int k = 0; k < 64; ++k) p *= ld_in(xin, t * 64 + k, mode);
        double a1r = lo1[0], a1i = lo1[1];
        double a2r = lo2[0], a2i = lo2[1] + (p < 0.0 ? PI_D : 0.0);
        double m = fmax(a1r, a2r);
        double s1, c1, s2, c2;
        sincos(a1i, &s1, &c1);
        sincos(a2i, &s2, &c2);
        double e1 = exp(a1r - m), e2 = exp(a2r - m);
        double zr = e1 * c1 + e2 * c2;
        double zi = e1 * s1 + e2 * s2;
        double outre = m + 0.5 * log(zr * zr + zi * zi);
        double outim = atan2(zi, zr);
        if (out_size >= 256) {                 // fallback: complex interleaved
            out[2 * t]     = (float)outre;
            out[2 * t + 1] = (float)outim;
        } else if (t < out_size) {             // primary: real part only (128)
            out[t] = (float)outre;
        }
    }
    for (int q = 256 + t; q < out_size; q += blockDim.x) out[q] = 0.0f;
}

extern "C" void kernel_launch(void* const* d_in, const int* in_sizes, int n_in,
                              void* d_out, int out_size, void* d_ws, size_t ws_size,
                              hipStream_t stream) {
    (void)ws_size;
    int xi = 0;
    for (int i = 0; i < n_in; ++i) if (in_sizes[i] == 8192) { xi = i; break; }
    const void* x = d_in[xi];
    const void* hh[2] = {nullptr, nullptr};
    int np = 0;
    for (int i = 0; i < n_in && np < 2; ++i) if (i != xi) hh[np++] = d_in[i];

    double* lows = (double*)d_ws;   // 512 doubles, fully rewritten every call

    GaussianState_24318104830346_kernel<<<256, 512, 0, stream>>>(x, hh[0], hh[1], lows);
    gs_combine<<<1, 256, 0, stream>>>(x, lows, (float*)d_out, out_size);
}

// Round 18
// 75.919 us; speedup vs baseline: 6.7293x; 1.0904x over previous
//
#include <hip/hip_runtime.h>
#include <hip/hip_bf16.h>
#include <math.h>

// ---------------------------------------------------------------------------
// GaussianState: out(b) = Re logsumexp( lo(b,0), log(prod s)+lo(b,1) )
//   lo(b,h) = log Pf(W) + 63*ln2 - i*pi + lt(h);  lt = -sum(v^2)/8
// W: 128x128 complex skew, interleaved order; rank-2 Parlett-Reid, static 2x2
// pivots, deferred log (s = prod 2*a_k). Round 18: 1024-thread block
// (16 waves = 4/SIMD) to fill the ~70% per-step barrier/latency bubble
// measured at 512 threads. Thread t: wave w=t>>6 owns cols [8w,8w+8)
// (col-retirement wave-uniform, k < 4w+3); rows q=t&63 + {0,64}
// (stratum 0 retires at k>30). acc[2][8] f32x2 ~= 32 VGPR; total ~95 < 128
// cap at 4 waves/EU (the allocator constraint rounds 14-16 established).
// ---------------------------------------------------------------------------

#define PI_D  3.14159265358979323846264338328
#define LN2_D 0.69314718055994530941723212146

typedef float f32x2 __attribute__((ext_vector_type(2)));

__device__ __forceinline__ int sniff_mode(const void* x) {
    const unsigned int* u = (const unsigned int*)x;
    unsigned int lo = u[0], hi = u[1];
    if ((hi == 0x3FF00000u || hi == 0xBFF00000u) && lo == 0u) return 1;       // f64
    unsigned short a = (unsigned short)(lo & 0xFFFFu);
    unsigned short b = (unsigned short)(lo >> 16);
    if ((a == 0x3F80u || a == 0xBF80u) && (b == 0x3F80u || b == 0xBF80u)) return 2; // bf16
    return 0;                                                                  // f32
}

__device__ __forceinline__ double ld_in(const void* p, int idx, int mode) {
    if (mode == 1) return ((const double*)p)[idx];
    if (mode == 2) {
        unsigned int w = ((unsigned int)((const unsigned short*)p)[idx]) << 16;
        return (double)__uint_as_float(w);
    }
    return (double)((const float*)p)[idx];
}

// G(p,q) = -H[p][q]/2 from upper-tri storage of H (f32)
__device__ __forceinline__ float Gq(const float* Hu, int p, int q) {
    if (p == q) return 0.0f;
    int i = (p < q) ? p : q;
    int j = (p < q) ? q : p;
    float g = -0.5f * Hu[(i * (255 - i)) / 2 + (j - i - 1)];
    return (p < q) ? g : -g;
}

// W'(rn,cn) in interleaved order: even index -> old top q=n>>1, odd -> bottom.
__device__ __forceinline__ void Wq(const float* Hu, const float* tsg,
                                   int rn, int cn, float& re, float& im) {
    int A = rn >> 1, B = cn >> 1;
    if ((cn & 1) == 0) {
        if ((rn & 1) == 0) {
            re = 0.5f * (-Gq(Hu, 2*A, 2*B)   + Gq(Hu, 2*A+1, 2*B+1));
            im = 0.5f * (-Gq(Hu, 2*A, 2*B+1) - Gq(Hu, 2*A+1, 2*B));
        } else {
            int pA = (A + 1) & 63; float tA = tsg[A];
            float Fre = 0.5f * ( tA * Gq(Hu, 2*B, 2*A+1) + Gq(Hu, 2*B+1, 2*pA) );
            float Fim = 0.5f * ( -Gq(Hu, 2*B, 2*pA) + tA * Gq(Hu, 2*B+1, 2*A+1) );
            float Mim = 0.5f * ((B == A ? tA : 0.0f) - (B == pA ? 1.0f : 0.0f));
            re = Fre; im = Mim + Fim;
        }
    } else {
        if ((rn & 1) == 0) {
            int pB = (B + 1) & 63; float tB = tsg[B];
            float Fre = 0.5f * ( tB * Gq(Hu, 2*A, 2*B+1) + Gq(Hu, 2*A+1, 2*pB) );
            float Fim = 0.5f * ( -Gq(Hu, 2*A, 2*pB) + tB * Gq(Hu, 2*A+1, 2*B+1) );
            float Mim = 0.5f * ((A == B ? tB : 0.0f) - (A == pB ? 1.0f : 0.0f));
            re = -Fre; im = -Mim - Fim;
        } else {
            int pA = (A + 1) & 63, pB = (B + 1) & 63;
            float tA = tsg[A], tB = tsg[B];
            re = 0.5f * ( -tA * tB * Gq(Hu, 2*A+1, 2*B+1) + Gq(Hu, 2*pA, 2*pB) );
            im = 0.5f * (  tA * Gq(Hu, 2*A+1, 2*pB) + tB * Gq(Hu, 2*pA, 2*B+1) );
        }
    }
}

// --- per-(sample,ham) Pfaffian via 2x2-pivot block elimination -------------
// grid 256 = (b,h); 1024 threads: wave w=t>>6 -> cols [8w,8w+8),
// q=t&63 -> rows {q, q+64}.
extern "C" __global__ void __launch_bounds__(1024)
GaussianState_24318104830346_kernel(const void* xin, const void* h1,
                                    const void* h2, double* lows) {
    const int t   = threadIdx.x;
    const int bid = blockIdx.x;
    const int b = bid & 127, h = bid >> 7;
    const int w    = t >> 6;                  // wave id = col group (uniform)
    const int q    = t & 63;                  // row base
    const int lane = t & 63;

    __shared__ float  tsg[64];
    __shared__ float4 xbuf[2][136];           // XI16-padded staged col pairs
    __shared__ double red[16];
    __shared__ float  Hu[8128];

    const int mode = sniff_mode(xin);
    const void* raw = h ? h2 : h1;

    // stage upper-tri H + accumulate sum(v^2) for lt
    double ss = 0.0;
    for (int f = t; f < 8128; f += 1024) {
        double v = ld_in(raw, f, mode);
        Hu[f] = (float)v;
        ss += v * v;
    }
#pragma unroll
    for (int off = 32; off >= 1; off >>= 1) ss += __shfl_xor(ss, off, 64);
    if (lane == 0) red[w] = ss;

    if (t < 64) {
        float sA = (float)ld_in(xin, b * 64 + t, mode);
        float sB = (float)ld_in(xin, b * 64 + ((t + 1) & 63), mode);
        float tt = sA * sB;
        if (t == 63) tt = -tt;
        tsg[t] = tt;
    }
    __syncthreads();

    // build W' fragment: 2 strata x 8 cols, packed (re,im) in f32x2
    f32x2 acc[2][8];
#pragma unroll
    for (int s = 0; s < 2; ++s)
#pragma unroll
        for (int j = 0; j < 8; ++j) {
            float re, im;
            Wq(Hu, tsg, q + 64 * s, 8 * w + j, re, im);
            acc[s][j] = (f32x2){re, im};
        }

    const int cb  = 8 * w + (w >> 1);         // XI16 base of col range (uniform)
    const int obq = q + (q >> 4);             // XI16 idx of row q (+68 for q+64)

    float sgr = 1.0f, sgi = 0.0f;             // s = prod 2*a_k (all threads)

    for (int K = 0; K < 16; ++K) {
#pragma unroll
        for (int m = 0; m < 4; ++m) {
            const int k = (K << 2) + m;
            if (k < 63) {
                const int par = m & 1;
                // stage pivot col pair 2k,2k+1 (owner wave; both strata)
                if (w == K) {
                    const int j2 = 2 * m;              // static
                    xbuf[par][obq] =
                        make_float4(acc[0][j2].x, acc[0][j2].y,
                                    acc[0][j2 + 1].x, acc[0][j2 + 1].y);
                    xbuf[par][obq + 68] =
                        make_float4(acc[1][j2].x, acc[1][j2].y,
                                    acc[1][j2 + 1].x, acc[1][j2 + 1].y);
                }
                __syncthreads();
                // pivot + sign (all threads; keeps history valid everywhere)
                float4 pv = xbuf[par][2 * k + (k >> 3)]; // XI16(2k), broadcast
                float arr = pv.z, aii = pv.w;
                float m2  = arr * arr + aii * aii;
                float den = __builtin_amdgcn_rcpf(m2);
                float ivr = arr * den, ivi = -aii * den;
                float nsr = 2.0f * (sgr * arr - sgi * aii);
                sgi = 2.0f * (sgr * aii + sgi * arr);
                sgr = nsr;
                if (k < 4 * w + 3) {                   // col-live (wave-uniform)
                    // read the 8 column values ONCE (broadcast across lanes)
                    const float4* bp = &xbuf[par][cb];
                    f32x2 c1[8], c2[8];
#pragma unroll
                    for (int j = 0; j < 8; ++j) {
                        float4 cv = bp[j];
                        c1[j] = (f32x2){cv.x, cv.y};
                        c2[j] = (f32x2){cv.z, cv.w};
                    }
#pragma unroll
                    for (int s = 0; s < 2; ++s) {
                        if (s == 1 || k <= 30) {       // row-live (uniform)
                            float4 own = xbuf[par][obq + 68 * s];
                            float br = own.z * ivr - own.w * ivi;
                            float bi = own.z * ivi + own.w * ivr;
                            float gr = own.x * ivr - own.y * ivi;
                            float gi = own.x * ivi + own.y * ivr;
                            f32x2 bv  = (f32x2){ br,  br};
                            f32x2 bnv = (f32x2){-bi,  bi};
                            f32x2 gv  = (f32x2){-gr, -gr};
                            f32x2 gnv = (f32x2){ gi, -gi};
#pragma unroll
                            for (int j = 0; j < 8; ++j) {
                                f32x2 a = acc[s][j];
                                a = __builtin_elementwise_fma(bv,  c1[j],    a);
                                a = __builtin_elementwise_fma(bnv, c1[j].yx, a);
                                a = __builtin_elementwise_fma(gv,  c2[j],    a);
                                a = __builtin_elementwise_fma(gnv, c2[j].yx, a);
                                acc[s][j] = a;
                            }
                        }
                    }
                }
            }
        }
    }

    __syncthreads();
    if (t == 1022)                            // row 126 (q=62,s=1), col 127 (w=15,j=7)
        xbuf[0][0] = make_float4(acc[1][7].x, acc[1][7].y, 0.0f, 0.0f);
    __syncthreads();
    if (t == 0) {
        float lr = xbuf[0][0].x, li = xbuf[0][0].y;      // a_63
        float snr = sgr * lr - sgi * li;       // s * a_63, |.| = 2^63 |Pf|
        float sni = sgr * li + sgi * lr;
        float mag = sqrtf(snr * snr + sni * sni);
        double sred = 0.0;
#pragma unroll
        for (int i = 0; i < 16; ++i) sred += red[i];
        double lt = -sred / 8.0;               // tr(H^2)/16 = -sum(v^2)/8
        double* lo = lows + (h * 128 + b) * 2;
        lo[0] = (double)logf(mag) + lt;        // = log|Pf| + 63 ln2 + lt
        lo[1] = atan2((double)sni, (double)snr) - PI_D;
    }
}

// --- combine: out(b) = Re logsumexp(lo1, log(s_prod)+lo2) as f32 -----------
extern "C" __global__ void gs_combine(const void* xin, const double* lows,
                                      float* out, int out_size) {
    int t = threadIdx.x;
    int mode = sniff_mode(xin);
    if (t < 128) {
        const double* lo1 = lows + t * 2;
        const double* lo2 = lows + (128 + t) * 2;
        double p = 1.0;
        for (int k = 0; k < 64; ++k) p *= ld_in(xin, t * 64 + k, mode);
        double a1r = lo1[0], a1i = lo1[1];
        double a2r = lo2[0], a2i = lo2[1] + (p < 0.0 ? PI_D : 0.0);
        double m = fmax(a1r, a2r);
        double s1, c1, s2, c2;
        sincos(a1i, &s1, &c1);
        sincos(a2i, &s2, &c2);
        double e1 = exp(a1r - m), e2 = exp(a2r - m);
        double zr = e1 * c1 + e2 * c2;
        double zi = e1 * s1 + e2 * s2;
        double outre = m + 0.5 * log(zr * zr + zi * zi);
        double outim = atan2(zi, zr);
        if (out_size >= 256) {                 // fallback: complex interleaved
            out[2 * t]     = (float)outre;
            out[2 * t + 1] = (float)outim;
        } else if (t < out_size) {             // primary: real part only (128)
            out[t] = (float)outre;
        }
    }
    for (int q = 256 + t; q < out_size; q += blockDim.x) out[q] = 0.0f;
}

extern "C" void kernel_launch(void* const* d_in, const int* in_sizes, int n_in,
                              void* d_out, int out_size, void* d_ws, size_t ws_size,
                              hipStream_t stream) {
    (void)ws_size;
    int xi = 0;
    for (int i = 0; i < n_in; ++i) if (in_sizes[i] == 8192) { xi = i; break; }
    const void* x = d_in[xi];
    const void* hh[2] = {nullptr, nullptr};
    int np = 0;
    for (int i = 0; i < n_in && np < 2; ++i) if (i != xi) hh[np++] = d_in[i];

    double* lows = (double*)d_ws;   // 512 doubles, fully rewritten every call

    GaussianState_24318104830346_kernel<<<256, 1024, 0, stream>>>(x, hh[0], hh[1], lows);
    gs_combine<<<1, 256, 0, stream>>>(x, lows, (float*)d_out, out_size);
}